// Round 1
// baseline (3013.132 us; speedup 1.0000x reference)
//
#include <hip/hip_runtime.h>

// AttentionMatcher: out = gate * softmax(N M^T, diag<-0) M + (1-gate) * N
// Flash-style (no n x n materialization). fp32 vector-ALU version (round 1:
// correctness baseline; MFMA bf16-split planned next).
//
// Layout decisions:
//  - BQ=32 query rows per block, BJ=32 key rows per tile, 256 threads.
//  - LDS tile row stride 260 floats: 260*4=1040 bytes (16B aligned for
//    float4 staging stores), 260%32==4 so row j starts at bank 4j%32.
//  - thread t owns query q=t>>3, and j / d indices interleaved as
//    (t&7)+8k  -> every wave LDS access lands on 8 distinct banks with
//    8-lane same-address broadcast (conflict-free; verified by hand above).

constexpr int EMBED = 256;
constexpr int BQ = 32;
constexpr int BJ = 32;
constexpr int TS = 260;       // LDS tile row stride (floats)
constexpr int NTHREADS = 256;

__launch_bounds__(NTHREADS, 1)
__global__ void attn_matcher_f32(const float* __restrict__ M,
                                 const float* __restrict__ Nmat,
                                 const float* __restrict__ Wg,
                                 const float* __restrict__ bg,
                                 const float* __restrict__ gate_b,
                                 const int* __restrict__ iseval_p,
                                 float* __restrict__ out,
                                 int n)
{
    __shared__ __align__(16) float Ns[BQ * TS];
    __shared__ __align__(16) float Ms[BJ * TS];
    __shared__ float Ps[BQ * 33];
    __shared__ float Wgs[EMBED];
    __shared__ float m_s[BQ], l_s[BQ], alpha_s[BQ], gates[BQ];
    __shared__ float gp[BQ * 9];

    const int t  = threadIdx.x;
    const int q  = t >> 3;      // 0..31 local query row
    const int t7 = t & 7;       // 0..7
    const int q0 = blockIdx.x * BQ;
    const int qg = q0 + q;      // global query row
    const int iseval = *iseval_p;

    // stage Wg and the N tile (rows q0..q0+BQ-1)
    Wgs[t] = Wg[t];   // NTHREADS == EMBED
    {
        const float4* src = (const float4*)(Nmat + (size_t)q0 * EMBED);
        for (int idx = t; idx < BQ * (EMBED / 4); idx += NTHREADS) {
            int row = idx >> 6;          // EMBED/4 = 64 float4 per row
            int c4  = idx & 63;
            float4 v = src[row * 64 + c4];
            *((float4*)&Ns[row * TS + c4 * 4]) = v;   // byte off 1040*row+16*c4
        }
    }
    if (t < BQ) { m_s[t] = -1e30f; l_s[t] = 0.f; }
    __syncthreads();

    // O accumulator: thread owns (q, d = t7 + 8k), k = 0..31
    float Oacc[32];
    #pragma unroll
    for (int k = 0; k < 32; ++k) Oacc[k] = 0.f;

    for (int j0 = 0; j0 < n; j0 += BJ) {
        // --- stage M tile (rows j0..j0+BJ-1) ---
        {
            const float4* src = (const float4*)(M + (size_t)j0 * EMBED);
            for (int idx = t; idx < BJ * (EMBED / 4); idx += NTHREADS) {
                int row = idx >> 6;
                int c4  = idx & 63;
                float4 v = src[row * 64 + c4];
                *((float4*)&Ms[row * TS + c4 * 4]) = v;
            }
        }
        __syncthreads();

        // --- scores: s_k = dot(N[q], M[j0 + t7 + 8k]) ---
        float s0 = 0.f, s1 = 0.f, s2 = 0.f, s3 = 0.f;
        {
            const float* an = &Ns[q * TS];
            const float* b0 = &Ms[(t7 + 0)  * TS];
            const float* b1 = &Ms[(t7 + 8)  * TS];
            const float* b2 = &Ms[(t7 + 16) * TS];
            const float* b3 = &Ms[(t7 + 24) * TS];
            #pragma unroll 8
            for (int d = 0; d < EMBED; ++d) {
                float a = an[d];
                s0 = fmaf(a, b0[d], s0);
                s1 = fmaf(a, b1[d], s1);
                s2 = fmaf(a, b2[d], s2);
                s3 = fmaf(a, b3[d], s3);
            }
        }

        // --- mask: training zeroes diag score; eval zeroes all of row 0 ---
        if (iseval) {
            if (qg == 0) { s0 = 0.f; s1 = 0.f; s2 = 0.f; s3 = 0.f; }
        } else {
            int dj = qg - j0;            // local j of the diagonal, if in tile
            if (dj == t7 + 0)  s0 = 0.f;
            if (dj == t7 + 8)  s1 = 0.f;
            if (dj == t7 + 16) s2 = 0.f;
            if (dj == t7 + 24) s3 = 0.f;
        }

        // --- online softmax: row max across the 8 threads sharing q ---
        float mx = fmaxf(fmaxf(s0, s1), fmaxf(s2, s3));
        gp[q * 9 + t7] = mx;
        __syncthreads();
        if (t < BQ) {
            float m_old = m_s[t];
            float mrow = m_old;
            #pragma unroll
            for (int i = 0; i < 8; ++i) mrow = fmaxf(mrow, gp[t * 9 + i]);
            m_s[t] = mrow;
            alpha_s[t] = __expf(m_old - mrow);
        }
        __syncthreads();

        float mnew = m_s[q];
        float aq   = alpha_s[q];
        #pragma unroll
        for (int k = 0; k < 32; ++k) Oacc[k] *= aq;

        float p0 = __expf(s0 - mnew);
        float p1 = __expf(s1 - mnew);
        float p2 = __expf(s2 - mnew);
        float p3 = __expf(s3 - mnew);
        Ps[q * 33 + t7 + 0]  = p0;
        Ps[q * 33 + t7 + 8]  = p1;
        Ps[q * 33 + t7 + 16] = p2;
        Ps[q * 33 + t7 + 24] = p3;
        gp[q * 9 + t7] = p0 + p1 + p2 + p3;
        __syncthreads();

        if (t < BQ) {  // runs concurrently with PV below on other lanes — safe
            float s = 0.f;
            #pragma unroll
            for (int i = 0; i < 8; ++i) s += gp[t * 9 + i];
            l_s[t] = l_s[t] * alpha_s[t] + s;
        }

        // --- PV accumulate: O[q][d] += sum_j P[q][j] * M[j][d] ---
        {
            const float* prow = &Ps[q * 33];
            #pragma unroll 4
            for (int j = 0; j < BJ; ++j) {
                float p = prow[j];
                const float* mr = &Ms[j * TS + t7];
                #pragma unroll
                for (int k = 0; k < 32; ++k)
                    Oacc[k] = fmaf(p, mr[8 * k], Oacc[k]);
            }
        }
        __syncthreads();   // protect Ms/Ps/l_s before next tile
    }

    // --- epilogue: normalize, gate, blend with N, store ---
    float linv = 1.f / l_s[q];
    #pragma unroll
    for (int k = 0; k < 32; ++k) Oacc[k] *= linv;

    float gpart = 0.f;
    #pragma unroll
    for (int k = 0; k < 32; ++k) gpart += Oacc[k] * Wgs[t7 + 8 * k];
    gp[q * 9 + t7] = gpart;
    __syncthreads();
    if (t < BQ) {
        float s = 0.f;
        #pragma unroll
        for (int i = 0; i < 8; ++i) s += gp[t * 9 + i];
        float logit = s + bg[0] + gate_b[0];
        gates[t] = 1.f / (1.f + __expf(-logit));
    }
    __syncthreads();

    float g = gates[q];
    float* orow = out + (size_t)qg * EMBED;
    const float* nrow = &Ns[q * TS];
    #pragma unroll
    for (int k = 0; k < 32; ++k) {
        int dd = t7 + 8 * k;
        orow[dd] = Oacc[k] * g + nrow[dd] * (1.f - g);
    }
}

extern "C" void kernel_launch(void* const* d_in, const int* in_sizes, int n_in,
                              void* d_out, int out_size, void* d_ws, size_t ws_size,
                              hipStream_t stream) {
    const float* M       = (const float*)d_in[0];
    const float* Nmat    = (const float*)d_in[1];
    const float* Wg      = (const float*)d_in[2];
    const float* bg      = (const float*)d_in[3];
    const float* gate_b  = (const float*)d_in[4];
    const int*   iseval  = (const int*)d_in[5];
    float* out = (float*)d_out;

    int n = in_sizes[0] / EMBED;   // 8192
    dim3 grid(n / BQ);             // 256 blocks, 1 per CU
    dim3 block(NTHREADS);
    hipLaunchKernelGGL(attn_matcher_f32, grid, block, 0, stream,
                       M, Nmat, Wg, bg, gate_b, iseval, out, n);
}

// Round 2
// 635.963 us; speedup vs baseline: 4.7379x; 4.7379x over previous
//
#include <hip/hip_runtime.h>

// AttentionMatcher MFMA version.
// out = gate * softmax(N M^T, diag<-0) M + (1-gate) * N,  n=8192, d=256, fp32.
// Flash-style, BQ=32 queries/block (grid=256), BJ=32 key tile, 256 threads.
// QK^T: bf16 hi/lo 3-MFMA split (fp32-grade scores). PV: single bf16 (P,M RNE).
// LDS: double-buffered {Mhi,Mlo row-major XOR-swizzled; Mt transposed} staging.

constexpr int EMBED = 256;
constexpr int BQ = 32;
constexpr int BJ = 32;
constexpr int NT = 256;

// LDS pool layout (bytes)
constexpr int MH_BYTES   = BJ * 512;                 // 32 rows x 256 bf16 (swizzled chunks)
constexpr int MT_STRIDE  = 36;                        // bf16 units per Mt row (72 B)
constexpr int MT_BYTES   = EMBED * MT_STRIDE * 2;     // 18432
constexpr int STAGE_B    = 2 * MH_BYTES + MT_BYTES;   // 51200 per buffer
constexpr int SS_OFF     = 2 * STAGE_B;               // fp32 scores 32 x 36
constexpr int SS_STRIDE  = 36;
constexpr int PH_OFF     = SS_OFF + 32 * SS_STRIDE * 4;
constexpr int PH_STRIDE  = 40;                        // bf16 units per P row
constexpr int MS_OFF     = PH_OFF + 32 * PH_STRIDE * 2;
constexpr int LS_OFF     = MS_OFF + 128;
constexpr int AS_OFF     = LS_OFF + 128;
constexpr int WG_OFF     = AS_OFF + 128;
constexpr int TOTAL_LDS  = WG_OFF + EMBED * 4;        // ~110 KB

typedef short short8v __attribute__((ext_vector_type(8)));
typedef short short4v __attribute__((ext_vector_type(4)));
typedef float f32x4   __attribute__((ext_vector_type(4)));

static __device__ inline short bft(float x) {        // bf16 truncate (hi)
    return (short)(__builtin_bit_cast(unsigned int, x) >> 16);
}
static __device__ inline float bfhf(float x) {       // hi as fp32
    return __builtin_bit_cast(float, __builtin_bit_cast(unsigned int, x) & 0xffff0000u);
}
static __device__ inline short bfr(float x) {        // bf16 RNE
    unsigned u = __builtin_bit_cast(unsigned int, x);
    return (short)((u + 0x7fffu + ((u >> 16) & 1u)) >> 16);
}
static __device__ inline f32x4 mfma_bf16(short8v a, short8v b, f32x4 c) {
    return __builtin_amdgcn_mfma_f32_16x16x32_bf16(a, b, c, 0, 0, 0);
}

__launch_bounds__(NT, 1)
__global__ void attn_mfma(const float* __restrict__ Mg,
                          const float* __restrict__ Ng,
                          const float* __restrict__ Wg,
                          const float* __restrict__ bg,
                          const float* __restrict__ gb,
                          const int* __restrict__ iseval_p,
                          float* __restrict__ out,
                          int n)
{
    __shared__ __align__(16) char smem[TOTAL_LDS];
    float* SS = (float*)(smem + SS_OFF);
    short* PH = (short*)(smem + PH_OFF);
    float* MS = (float*)(smem + MS_OFF);
    float* LS = (float*)(smem + LS_OFF);
    float* AS = (float*)(smem + AS_OFF);
    float* WGS = (float*)(smem + WG_OFF);

    const int t    = threadIdx.x;
    const int lane = t & 63;
    const int wave = t >> 6;
    const int quad = lane >> 4;
    const int mn   = lane & 15;
    const int qh   = wave & 1;      // q-half (QK + PV)
    const int jh   = wave >> 1;     // j-half (QK)
    const int dh   = wave >> 1;     // d-half (PV)
    const int q0   = blockIdx.x * BQ;
    const int iseval = *iseval_p;
    const int ntiles = n / BJ;

    // staging thread mapping
    const int sr = t >> 3;          // row 0..31
    const int sh = t & 7;
    const int sr7 = sr & 7;

    // ---- prologue: Wg, softmax state ----
    WGS[t] = Wg[t];
    if (t < BQ) { MS[t] = -1e30f; LS[t] = 0.f; }

    // ---- Q fragment preload (A-layout, hi/lo) ----
    short8v Qh[8], Ql[8];
    {
        const int qrow = q0 + qh * 16 + mn;
        const float* np = Ng + (size_t)qrow * EMBED;
        #pragma unroll
        for (int ks = 0; ks < 8; ++ks) {
            const float* p = np + ks * 32 + quad * 8;
            float4 a = *(const float4*)p;
            float4 b = *(const float4*)(p + 4);
            float xs[8] = {a.x,a.y,a.z,a.w,b.x,b.y,b.z,b.w};
            short8v h, l;
            #pragma unroll
            for (int e = 0; e < 8; ++e) {
                float x = xs[e];
                h[e] = bft(x);
                l[e] = bft(x - bfhf(x));
            }
            Qh[ks] = h; Ql[ks] = l;
        }
    }

    // ---- stage tile 0 into buffer 0 ----
    {
        const float4* src = (const float4*)Mg;
        char* mh = smem; char* ml = smem + MH_BYTES; char* mt = smem + 2*MH_BYTES;
        float4 v[8];
        #pragma unroll
        for (int i = 0; i < 8; ++i) v[i] = src[sr * 64 + sh + 8 * i];
        #pragma unroll
        for (int i = 0; i < 8; ++i) {
            int d0 = 4 * (sh + 8 * i);
            float xs[4] = {v[i].x, v[i].y, v[i].z, v[i].w};
            short4v hh, ll;
            #pragma unroll
            for (int k = 0; k < 4; ++k) {
                float x = xs[k];
                hh[k] = bft(x);
                ll[k] = bft(x - bfhf(x));
            }
            int off = sr * 512 + (((d0 >> 3) ^ sr7) << 4) + ((d0 >> 2) & 1) * 8;
            *(short4v*)(mh + off) = hh;
            *(short4v*)(ml + off) = ll;
            #pragma unroll
            for (int k = 0; k < 4; ++k)
                *(short*)(mt + (size_t)(d0 + k) * (MT_STRIDE*2) + sr * 2) = bfr(xs[k]);
        }
    }

    // ---- O accumulators (C-layout): 8 d-tiles x f32x4 ----
    f32x4 O[8];
    #pragma unroll
    for (int i = 0; i < 8; ++i) O[i] = (f32x4){0.f,0.f,0.f,0.f};

    __syncthreads();

    const int brow = jh * 16 + mn;     // B n-index = local M row (QK)
    const int br7  = brow & 7;

    for (int tile = 0; tile < ntiles; ++tile) {
        char* bufc = smem + (tile & 1) * STAGE_B;
        char* bufn = smem + ((tile + 1) & 1) * STAGE_B;
        const char* mh = bufc;
        const char* ml = bufc + MH_BYTES;
        const char* mt = bufc + 2 * MH_BYTES;
        const int j0 = tile * BJ;
        const bool have_next = (tile + 1) < ntiles;

        // --- prefetch next tile (global -> regs) ---
        float4 v[8];
        if (have_next) {
            const float4* src = (const float4*)(Mg + (size_t)(j0 + BJ) * EMBED);
            #pragma unroll
            for (int i = 0; i < 8; ++i) v[i] = src[sr * 64 + sh + 8 * i];
        }

        // --- QK^T: S-tile 16x16 per wave, 3-MFMA split over 8 k-steps ---
        {
            f32x4 acc = (f32x4){0.f,0.f,0.f,0.f};
            #pragma unroll
            for (int ks = 0; ks < 8; ++ks) {
                int c = 4 * ks + quad;
                int off = brow * 512 + ((c ^ br7) << 4);
                short8v bh = *(const short8v*)(mh + off);
                short8v bl = *(const short8v*)(ml + off);
                acc = mfma_bf16(Qh[ks], bh, acc);
                acc = mfma_bf16(Qh[ks], bl, acc);
                acc = mfma_bf16(Ql[ks], bh, acc);
            }
            #pragma unroll
            for (int r = 0; r < 4; ++r)
                SS[(qh * 16 + quad * 4 + r) * SS_STRIDE + jh * 16 + mn] = acc[r];
        }
        __syncthreads();   // (1) S ready

        // --- online softmax (8 threads per q-row, shuffle reductions) ---
        {
            const int q = sr;          // t>>3
            const int h = sh;
            const int qg = q0 + q;
            float s[4];
            #pragma unroll
            for (int m = 0; m < 4; ++m) s[m] = SS[q * SS_STRIDE + h + 8 * m];
            if (iseval) {
                if (qg == 0) { s[0]=0.f; s[1]=0.f; s[2]=0.f; s[3]=0.f; }
            } else {
                int dj = qg - j0;
                #pragma unroll
                for (int m = 0; m < 4; ++m) if (dj == h + 8 * m) s[m] = 0.f;
            }
            float mx = fmaxf(fmaxf(s[0], s[1]), fmaxf(s[2], s[3]));
            mx = fmaxf(mx, __shfl_xor(mx, 1));
            mx = fmaxf(mx, __shfl_xor(mx, 2));
            mx = fmaxf(mx, __shfl_xor(mx, 4));
            float m_old = MS[q];
            float m_new = fmaxf(m_old, mx);
            float alpha = __expf(m_old - m_new);
            float p[4], ps = 0.f;
            #pragma unroll
            for (int m = 0; m < 4; ++m) { p[m] = __expf(s[m] - m_new); ps += p[m]; }
            ps += __shfl_xor(ps, 1);
            ps += __shfl_xor(ps, 2);
            ps += __shfl_xor(ps, 4);
            if (h == 0) {
                MS[q] = m_new;
                AS[q] = alpha;
                LS[q] = LS[q] * alpha + ps;
            }
            #pragma unroll
            for (int m = 0; m < 4; ++m) PH[q * PH_STRIDE + h + 8 * m] = bfr(p[m]);
        }
        __syncthreads();   // (2) P, alpha ready

        // --- stage next tile (regs -> LDS, buffer nxt) ---
        if (have_next) {
            char* mh2 = bufn; char* ml2 = bufn + MH_BYTES; char* mt2 = bufn + 2*MH_BYTES;
            #pragma unroll
            for (int i = 0; i < 8; ++i) {
                int d0 = 4 * (sh + 8 * i);
                float xs[4] = {v[i].x, v[i].y, v[i].z, v[i].w};
                short4v hh, ll;
                #pragma unroll
                for (int k = 0; k < 4; ++k) {
                    float x = xs[k];
                    hh[k] = bft(x);
                    ll[k] = bft(x - bfhf(x));
                }
                int off = sr * 512 + (((d0 >> 3) ^ sr7) << 4) + ((d0 >> 2) & 1) * 8;
                *(short4v*)(mh2 + off) = hh;
                *(short4v*)(ml2 + off) = ll;
                #pragma unroll
                for (int k = 0; k < 4; ++k)
                    *(short*)(mt2 + (size_t)(d0 + k) * (MT_STRIDE*2) + sr * 2) = bfr(xs[k]);
            }
        }

        // --- PV: rescale O by alpha, accumulate P * M ---
        {
            float aq[4];
            #pragma unroll
            for (int r = 0; r < 4; ++r) aq[r] = AS[qh * 16 + quad * 4 + r];
            short8v pa = *(const short8v*)(PH + (qh * 16 + mn) * PH_STRIDE + quad * 8);
            #pragma unroll
            for (int dt = 0; dt < 8; ++dt) {
                int drow = dh * 128 + dt * 16 + mn;
                const char* base = mt + (size_t)drow * (MT_STRIDE*2) + (quad << 4);
                short4v x = *(const short4v*)base;
                short4v y = *(const short4v*)(base + 8);
                short8v f = __builtin_shufflevector(x, y, 0,1,2,3,4,5,6,7);
                f32x4 o = O[dt];
                o[0] *= aq[0]; o[1] *= aq[1]; o[2] *= aq[2]; o[3] *= aq[3];
                O[dt] = mfma_bf16(pa, f, o);
            }
        }
        __syncthreads();   // (3) staging done / buffers safe to swap
    }

    // ---- epilogue: normalize, write O to LDS, gate, blend, store ----
    {
        float linv[4];
        #pragma unroll
        for (int r = 0; r < 4; ++r) linv[r] = 1.f / LS[qh * 16 + quad * 4 + r];
        float* OS = (float*)smem;      // alias buffers (dead): 32 x 260 fp32
        #pragma unroll
        for (int dt = 0; dt < 8; ++dt) {
            #pragma unroll
            for (int r = 0; r < 4; ++r) {
                int q = qh * 16 + quad * 4 + r;
                int d = dh * 128 + dt * 16 + mn;
                OS[q * 260 + d] = O[dt][r] * linv[r];
            }
        }
    }
    __syncthreads();
    {
        float* OS = (float*)smem;
        const int q = sr, h = sh;
        const int qg = q0 + q;
        const float4* osr = (const float4*)(OS + q * 260 + h * 32);
        const float4* wgr = (const float4*)(WGS + h * 32);
        float dot = 0.f;
        #pragma unroll
        for (int i = 0; i < 8; ++i) {
            float4 o = osr[i], w = wgr[i];
            dot += o.x*w.x + o.y*w.y + o.z*w.z + o.w*w.w;
        }
        dot += __shfl_xor(dot, 1);
        dot += __shfl_xor(dot, 2);
        dot += __shfl_xor(dot, 4);
        float logit = dot + bg[0] + gb[0];
        float g = 1.f / (1.f + __expf(-logit));
        const float4* n4 = (const float4*)(Ng + (size_t)qg * EMBED + h * 32);
        float4* o4 = (float4*)(out + (size_t)qg * EMBED + h * 32);
        #pragma unroll
        for (int i = 0; i < 8; ++i) {
            float4 o = osr[i], nn = n4[i];
            float4 res;
            res.x = o.x * g + nn.x * (1.f - g);
            res.y = o.y * g + nn.y * (1.f - g);
            res.z = o.z * g + nn.z * (1.f - g);
            res.w = o.w * g + nn.w * (1.f - g);
            o4[i] = res;
        }
    }
}

extern "C" void kernel_launch(void* const* d_in, const int* in_sizes, int n_in,
                              void* d_out, int out_size, void* d_ws, size_t ws_size,
                              hipStream_t stream) {
    const float* M      = (const float*)d_in[0];
    const float* N      = (const float*)d_in[1];
    const float* Wgp    = (const float*)d_in[2];
    const float* bgp    = (const float*)d_in[3];
    const float* gbp    = (const float*)d_in[4];
    const int*   iseval = (const int*)d_in[5];
    float* out = (float*)d_out;

    int n = in_sizes[0] / EMBED;     // 8192
    dim3 grid(n / BQ);               // 256
    dim3 block(NT);
    hipLaunchKernelGGL(attn_mfma, grid, block, 0, stream,
                       M, N, Wgp, bgp, gbp, iseval, out, n);
}

// Round 3
// 489.634 us; speedup vs baseline: 6.1538x; 1.2989x over previous
//
#include <hip/hip_runtime.h>

// AttentionMatcher R3: precomputed bf16 planes in d_ws + global_load_lds staging.
// out = gate * softmax(N M^T, diag<-0) M + (1-gate) * N,  n=8192, d=256, fp32.
//
// ws: MhG [n][256] bf16 hi-trunc, 16B-chunk XOR-swizzled by (j&7)
//     MlG [n][256] bf16 lo (bf16(x - hi))      , same swizzle
//     MtG [256][n] bf16 RNE, plain row-major (M transposed)
//
// Main kernel: 256 blocks x 512 thr (8 waves). BQ=32 queries/block, BJ=64 tile.
// QK: waves (jh 0..3, ksh 0..1), B-frag reused for both q-halves; 3-MFMA hi/lo
//     split; partial S in 2 LDS planes (summed in softmax).
// PV: waves (dh 0..3, kh 0..1); kh-partial O accumulators combined in epilogue.
// Mt LDS layout: 272B chunks = 2 d-rows of 128B + 16B pad  -> conflict-free
// b128 PV reads AND exactly matches global_load_lds(width=4) lane order.

constexpr int EMBED = 256;
constexpr int BQ = 32;
constexpr int BJ = 64;
constexpr int NT = 512;

// LDS offsets (bytes)
constexpr int MH_O  = 0;            // 64 rows x 512B
constexpr int ML_O  = 32768;
constexpr int MT0_O = 65536;        // 128 chunks x 272B
constexpr int MT1_O = 100352;
constexpr int SS_O  = 135168;       // 2 planes x (32 x 68 fp32) = 2 x 8704
constexpr int PH_O  = 152576;       // 32 x 144B (64 bf16 + pad)
constexpr int MS_O  = 157184;
constexpr int LS_O  = 157312;
constexpr int AS_O  = 157440;
constexpr int WG_O  = 157568;       // 256 fp32
constexpr int LDS_TOTAL = 158592;

typedef short short8v __attribute__((ext_vector_type(8)));
typedef float f32x4   __attribute__((ext_vector_type(4)));

static __device__ __forceinline__ unsigned fbits(float x) { return __builtin_bit_cast(unsigned, x); }
static __device__ __forceinline__ float bitsf(unsigned u) { return __builtin_bit_cast(float, u); }
static __device__ __forceinline__ unsigned short bfr(float x) {   // bf16 RNE
    unsigned u = fbits(x);
    return (unsigned short)((u + 0x7fffu + ((u >> 16) & 1u)) >> 16);
}
static __device__ __forceinline__ f32x4 mfma16(short8v a, short8v b, f32x4 c) {
    return __builtin_amdgcn_mfma_f32_16x16x32_bf16(a, b, c, 0, 0, 0);
}
static __device__ __forceinline__ void gld_lds16(const void* g, void* l) {
    __builtin_amdgcn_global_load_lds((const __attribute__((address_space(1))) unsigned int*)g,
                                     (__attribute__((address_space(3))) unsigned int*)l, 16, 0, 0);
}
static __device__ __forceinline__ void gld_lds4(const void* g, void* l) {
    __builtin_amdgcn_global_load_lds((const __attribute__((address_space(1))) unsigned int*)g,
                                     (__attribute__((address_space(3))) unsigned int*)l, 4, 0, 0);
}

// ---------- preprocess A: hi/lo planes with baked chunk swizzle ----------
__global__ void prep_hilo(const float* __restrict__ M,
                          short* __restrict__ MhG, short* __restrict__ MlG) {
    int g = blockIdx.x * 256 + threadIdx.x;       // n*16 threads total
    int j = g >> 4, seg = g & 15;                 // seg: 16-d chunk pair
    const float* src = M + (size_t)j * EMBED + seg * 16;
    short8v hA, hB, lA, lB;
    #pragma unroll
    for (int i = 0; i < 4; ++i) {
        float4 v = *(const float4*)(src + 4 * i);
        float xs[4] = {v.x, v.y, v.z, v.w};
        #pragma unroll
        for (int e = 0; e < 4; ++e) {
            unsigned u = fbits(xs[e]);
            short hi = (short)(u >> 16);
            float hif = bitsf(u & 0xffff0000u);
            short lo = (short)(fbits(xs[e] - hif) >> 16);
            int idx = 4 * i + e;
            if (idx < 8) { hA[idx] = hi; lA[idx] = lo; }
            else         { hB[idx - 8] = hi; lB[idx - 8] = lo; }
        }
    }
    int p0 = (2 * seg) ^ (j & 7), p1 = (2 * seg + 1) ^ (j & 7);
    short* hrow = MhG + (size_t)j * 256;
    short* lrow = MlG + (size_t)j * 256;
    *(short8v*)(hrow + p0 * 8) = hA;
    *(short8v*)(hrow + p1 * 8) = hB;
    *(short8v*)(lrow + p0 * 8) = lA;
    *(short8v*)(lrow + p1 * 8) = lB;
}

// ---------- preprocess B: transposed RNE plane ----------
__global__ void prep_mt(const float* __restrict__ M, short* __restrict__ MtG, int n) {
    __shared__ float L[64 * 68];
    int j0 = blockIdx.x * 64, d0 = blockIdx.y * 64;
    int t = threadIdx.x;
    {
        int lj = t >> 2, cc = (t & 3) * 16;
        const float* src = M + (size_t)(j0 + lj) * EMBED + d0 + cc;
        #pragma unroll
        for (int i = 0; i < 4; ++i)
            *(float4*)&L[lj * 68 + cc + 4 * i] = *(const float4*)(src + 4 * i);
    }
    __syncthreads();
    {
        int ld = t >> 2, jseg = (t & 3) * 16;
        unsigned w[8];
        #pragma unroll
        for (int i = 0; i < 8; ++i) {
            float x0 = L[(jseg + 2 * i) * 68 + ld];
            float x1 = L[(jseg + 2 * i + 1) * 68 + ld];
            w[i] = (unsigned)bfr(x0) | ((unsigned)bfr(x1) << 16);
        }
        short* dst = MtG + (size_t)(d0 + ld) * n + j0 + jseg;
        ((uint4*)dst)[0] = make_uint4(w[0], w[1], w[2], w[3]);
        ((uint4*)dst)[1] = make_uint4(w[4], w[5], w[6], w[7]);
    }
}

// ---------- main fused attention kernel ----------
__launch_bounds__(NT, 2)
__global__ void attn_main(const short* __restrict__ MhG, const short* __restrict__ MlG,
                          const short* __restrict__ MtG,
                          const float* __restrict__ Ng, const float* __restrict__ Wg,
                          const float* __restrict__ bg, const float* __restrict__ gb,
                          const int* __restrict__ iseval_p,
                          float* __restrict__ out, int n)
{
    __shared__ __align__(16) char smem[LDS_TOTAL];
    float* MS  = (float*)(smem + MS_O);
    float* LS  = (float*)(smem + LS_O);
    float* AS  = (float*)(smem + AS_O);
    float* WGS = (float*)(smem + WG_O);

    const int t = threadIdx.x, lane = t & 63, wave = t >> 6;
    const int quad = lane >> 4, mn = lane & 15;
    const int wA = wave & 1;    // ksh (QK) / kh (PV)
    const int wB = wave >> 1;   // jh  (QK) / dh (PV)
    const int q0 = blockIdx.x * BQ;
    const int iseval = *iseval_p;
    const int ntiles = n / BJ;
    const int sq = t >> 4, sh = t & 15;   // softmax / epilogue roles

    if (t < 256) WGS[t] = Wg[t];
    if (t < 32) { MS[t] = -1e30f; LS[t] = 0.f; }

    // ---- Q fragments (A-layout): [qh*4 + kk], ks = wA*4 + kk ----
    short8v Qh[8], Ql[8];
    #pragma unroll
    for (int qh = 0; qh < 2; ++qh)
        #pragma unroll
        for (int kk = 0; kk < 4; ++kk) {
            const float* p = Ng + (size_t)(q0 + qh * 16 + mn) * EMBED + (wA * 4 + kk) * 32 + quad * 8;
            float4 a = *(const float4*)p, b = *(const float4*)(p + 4);
            float xs[8] = {a.x, a.y, a.z, a.w, b.x, b.y, b.z, b.w};
            short8v h, l;
            #pragma unroll
            for (int e = 0; e < 8; ++e) {
                unsigned u = fbits(xs[e]);
                h[e] = (short)(u >> 16);
                l[e] = (short)(fbits(xs[e] - bitsf(u & 0xffff0000u)) >> 16);
            }
            Qh[qh * 4 + kk] = h; Ql[qh * 4 + kk] = l;
        }

    // ---- initial staging: tile 0 ----
    {
        const char* gh = (const char*)MhG;
        const char* gl = (const char*)MlG;
        #pragma unroll
        for (int i = 0; i < 4; ++i) {
            int blk = wave * 4 + i;
            gld_lds16(gh + blk * 1024 + lane * 16, smem + MH_O + blk * 1024);
            gld_lds16(gl + blk * 1024 + lane * 16, smem + ML_O + blk * 1024);
        }
        const short* gt = MtG + (size_t)(lane >> 5) * n + (lane & 31) * 2;  // j0 = 0
        for (int cp = wave; cp < 128; cp += 8)
            gld_lds4(gt + (size_t)(2 * cp) * n, smem + MT0_O + cp * 272);
    }

    f32x4 O[8];
    #pragma unroll
    for (int i = 0; i < 8; ++i) O[i] = (f32x4){0.f, 0.f, 0.f, 0.f};

    __syncthreads();

    const int brow = wB * 16 + mn;     // QK B-row (local j)
    const int swz  = brow & 7;

    for (int tile = 0; tile < ntiles; ++tile) {
        const char* mtc = smem + ((tile & 1) ? MT1_O : MT0_O);
        char*       mtn = smem + ((tile & 1) ? MT0_O : MT1_O);
        const int j0 = tile * BJ;
        const bool hn = (tile + 1) < ntiles;

        // --- issue Mt DMA for next tile (drained at sync1; covered by QK) ---
        if (hn) {
            const short* gt = MtG + (size_t)(lane >> 5) * n + (j0 + BJ) + (lane & 31) * 2;
            for (int cp = wave; cp < 128; cp += 8)
                gld_lds4(gt + (size_t)(2 * cp) * n, mtn + cp * 272);
        }

        // --- QK^T: partial S over this wave's 4 k-steps, both q-halves ---
        {
            f32x4 acc0 = (f32x4){0.f,0.f,0.f,0.f}, acc1 = (f32x4){0.f,0.f,0.f,0.f};
            #pragma unroll
            for (int kk = 0; kk < 4; ++kk) {
                int c = 4 * (wA * 4 + kk) + quad;
                int off = brow * 512 + ((c ^ swz) << 4);
                short8v bh = *(const short8v*)(smem + MH_O + off);
                short8v bl = *(const short8v*)(smem + ML_O + off);
                acc0 = mfma16(Qh[kk], bh, acc0);
                acc0 = mfma16(Qh[kk], bl, acc0);
                acc0 = mfma16(Ql[kk], bh, acc0);
                acc1 = mfma16(Qh[4 + kk], bh, acc1);
                acc1 = mfma16(Qh[4 + kk], bl, acc1);
                acc1 = mfma16(Ql[4 + kk], bh, acc1);
            }
            float* ss = (float*)(smem + SS_O) + wA * 2176;
            #pragma unroll
            for (int r = 0; r < 4; ++r) {
                ss[(quad * 4 + r) * 68 + wB * 16 + mn]        = acc0[r];
                ss[(16 + quad * 4 + r) * 68 + wB * 16 + mn]   = acc1[r];
            }
        }
        __syncthreads();   // sync1: SS visible; Mt DMA drained

        // --- issue Mh/Ml DMA for next tile (drained at sync2; covered by softmax) ---
        if (hn) {
            const char* gh = (const char*)MhG + (size_t)(j0 + BJ) * 512;
            const char* gl = (const char*)MlG + (size_t)(j0 + BJ) * 512;
            #pragma unroll
            for (int i = 0; i < 4; ++i) {
                int blk = wave * 4 + i;
                gld_lds16(gh + blk * 1024 + lane * 16, smem + MH_O + blk * 1024);
                gld_lds16(gl + blk * 1024 + lane * 16, smem + ML_O + blk * 1024);
            }
        }

        // --- online softmax: thread (sq, sh) owns j = 4sh..4sh+3 ---
        {
            const float* ss0 = (const float*)(smem + SS_O);
            float4 sa = *(const float4*)(ss0 + sq * 68 + 4 * sh);
            float4 sb = *(const float4*)(ss0 + 2176 + sq * 68 + 4 * sh);
            float s[4] = {sa.x + sb.x, sa.y + sb.y, sa.z + sb.z, sa.w + sb.w};
            const int qg = q0 + sq;
            if (iseval) {
                if (qg == 0) { s[0] = 0.f; s[1] = 0.f; s[2] = 0.f; s[3] = 0.f; }
            } else {
                int dj = qg - j0;
                int b4 = sh * 4;
                if (dj == b4)     s[0] = 0.f;
                if (dj == b4 + 1) s[1] = 0.f;
                if (dj == b4 + 2) s[2] = 0.f;
                if (dj == b4 + 3) s[3] = 0.f;
            }
            float mx = fmaxf(fmaxf(s[0], s[1]), fmaxf(s[2], s[3]));
            mx = fmaxf(mx, __shfl_xor(mx, 1));
            mx = fmaxf(mx, __shfl_xor(mx, 2));
            mx = fmaxf(mx, __shfl_xor(mx, 4));
            mx = fmaxf(mx, __shfl_xor(mx, 8));
            float m_old = MS[sq];
            float m_new = fmaxf(m_old, mx);
            float alpha = __expf(m_old - m_new);
            float p[4], ps = 0.f;
            #pragma unroll
            for (int m = 0; m < 4; ++m) { p[m] = __expf(s[m] - m_new); ps += p[m]; }
            ps += __shfl_xor(ps, 1);
            ps += __shfl_xor(ps, 2);
            ps += __shfl_xor(ps, 4);
            ps += __shfl_xor(ps, 8);
            if (sh == 0) {
                MS[sq] = m_new;
                AS[sq] = alpha;
                LS[sq] = LS[sq] * alpha + ps;
            }
            unsigned w0 = (unsigned)bfr(p[0]) | ((unsigned)bfr(p[1]) << 16);
            unsigned w1 = (unsigned)bfr(p[2]) | ((unsigned)bfr(p[3]) << 16);
            *(uint2*)(smem + PH_O + sq * 144 + sh * 8) = make_uint2(w0, w1);
        }
        __syncthreads();   // sync2: PH/AS visible; Mh/Ml DMA drained

        // --- PV: O[qh][dt] += P(qh,khalf) x Mt(dt,khalf), alpha-rescaled ---
        {
            float aq0[4], aq1[4];
            #pragma unroll
            for (int r = 0; r < 4; ++r) { aq0[r] = AS[quad * 4 + r]; aq1[r] = AS[16 + quad * 4 + r]; }
            short8v pa0 = *(const short8v*)(smem + PH_O + mn * 144 + wA * 64 + quad * 16);
            short8v pa1 = *(const short8v*)(smem + PH_O + (16 + mn) * 144 + wA * 64 + quad * 16);
            #pragma unroll
            for (int dt = 0; dt < 4; ++dt) {
                int d = wB * 64 + dt * 16 + mn;
                short8v bf = *(const short8v*)(mtc + (d >> 1) * 272 + (d & 1) * 128 + wA * 64 + quad * 16);
                f32x4 o = O[dt];
                o[0] *= aq0[0]; o[1] *= aq0[1]; o[2] *= aq0[2]; o[3] *= aq0[3];
                O[dt] = mfma16(pa0, bf, o);
                o = O[4 + dt];
                o[0] *= aq1[0]; o[1] *= aq1[1]; o[2] *= aq1[2]; o[3] *= aq1[3];
                O[4 + dt] = mfma16(pa1, bf, o);
            }
        }
        __syncthreads();   // sync3: PV done with mtc/PH before overwrite
    }

    // ---- epilogue: combine kh-halves, normalize, gate, blend, store ----
    float* comb = (float*)smem;                 // 32 KB over dead Mh
    if (wA == 1) {
        #pragma unroll
        for (int f = 0; f < 8; ++f)
            *(f32x4*)(comb + wB * 2048 + f * 256 + lane * 4) = O[f];
    }
    __syncthreads();
    if (wA == 0) {
        float* OS = (float*)(smem + 32768);     // 32 x 260 fp32 over dead Ml/Mt0
        float li0[4], li1[4];
        #pragma unroll
        for (int r = 0; r < 4; ++r) {
            li0[r] = 1.f / LS[quad * 4 + r];
            li1[r] = 1.f / LS[16 + quad * 4 + r];
        }
        #pragma unroll
        for (int f = 0; f < 8; ++f) {
            f32x4 oth = *(const f32x4*)(comb + wB * 2048 + f * 256 + lane * 4);
            f32x4 o = O[f];
            o[0] += oth[0]; o[1] += oth[1]; o[2] += oth[2]; o[3] += oth[3];
            int qh = f >> 2, dt = f & 3;
            int d = wB * 64 + dt * 16 + mn;
            #pragma unroll
            for (int r = 0; r < 4; ++r) {
                float li = qh ? li1[r] : li0[r];
                OS[(qh * 16 + quad * 4 + r) * 260 + d] = o[r] * li;
            }
        }
    }
    __syncthreads();
    {
        const float* OS = (const float*)(smem + 32768);
        const int qg = q0 + sq;
        float4 ov[4];
        float dot = 0.f;
        #pragma unroll
        for (int i = 0; i < 4; ++i) {
            ov[i] = *(const float4*)(OS + sq * 260 + sh * 16 + 4 * i);
            float4 w = *(const float4*)(WGS + sh * 16 + 4 * i);
            dot += ov[i].x * w.x + ov[i].y * w.y + ov[i].z * w.z + ov[i].w * w.w;
        }
        dot += __shfl_xor(dot, 1);
        dot += __shfl_xor(dot, 2);
        dot += __shfl_xor(dot, 4);
        dot += __shfl_xor(dot, 8);
        float g = 1.f / (1.f + __expf(-(dot + bg[0] + gb[0])));
        const float4* n4 = (const float4*)(Ng + (size_t)qg * EMBED + sh * 16);
        float4* o4 = (float4*)(out + (size_t)qg * EMBED + sh * 16);
        #pragma unroll
        for (int i = 0; i < 4; ++i) {
            float4 nn = n4[i];
            float4 res;
            res.x = ov[i].x * g + nn.x * (1.f - g);
            res.y = ov[i].y * g + nn.y * (1.f - g);
            res.z = ov[i].z * g + nn.z * (1.f - g);
            res.w = ov[i].w * g + nn.w * (1.f - g);
            o4[i] = res;
        }
    }
}

extern "C" void kernel_launch(void* const* d_in, const int* in_sizes, int n_in,
                              void* d_out, int out_size, void* d_ws, size_t ws_size,
                              hipStream_t stream) {
    const float* M      = (const float*)d_in[0];
    const float* N      = (const float*)d_in[1];
    const float* Wgp    = (const float*)d_in[2];
    const float* bgp    = (const float*)d_in[3];
    const float* gbp    = (const float*)d_in[4];
    const int*   iseval = (const int*)d_in[5];
    float* out = (float*)d_out;

    int n = in_sizes[0] / EMBED;   // 8192
    short* MhG = (short*)d_ws;                       // n*256 bf16
    short* MlG = MhG + (size_t)n * 256;
    short* MtG = MlG + (size_t)n * 256;              // 256 x n bf16
    // requires ws_size >= 3 * n * 256 * 2 = 12.6 MB at n=8192

    hipLaunchKernelGGL(prep_hilo, dim3(n * 16 / 256), dim3(256), 0, stream, M, MhG, MlG);
    hipLaunchKernelGGL(prep_mt, dim3(n / 64, EMBED / 64), dim3(256), 0, stream, M, MtG, n);
    hipLaunchKernelGGL(attn_main, dim3(n / BQ), dim3(NT), 0, stream,
                       MhG, MlG, MtG, N, Wgp, bgp, gbp, iseval, out, n);
}

// Round 4
// 236.113 us; speedup vs baseline: 12.7614x; 2.0737x over previous
//
#include <hip/hip_runtime.h>

// AttentionMatcher R4: fp16 MFMA + tile-major transposed plane + 2-way split-j.
// out = gate * softmax(N M^T, diag<-0) M + (1-gate) * N,  n=8192, d=256, fp32.
//
// ws: MhG [n][256] fp16 RNE, 16B-chunk XOR(j&7)-swizzled rows (QK B-plane)
//     MtG [n/64 tiles][256 d][64 j] fp16 RNE, XOR(d&7)-swizzled 128B rows
//         == exact per-tile LDS image -> staged with gld_lds16 only.
//     O1  [n][256] f32 partial (j-half 1); O0 partial lives in d_out.
//     MLm/MLl [2][n] f32 running max / sum per half.
//
// attn_split: grid 256 = (128 q-blocks x 2 j-halves), 512 thr, BQ=64, BJ=64.
//   QK: wave(jt,qp): 16 fp16 MFMAs, B-frag shared across 2 q-tiles.
//   PV: wave(dg,qh2): 16 fp16 MFMAs, P from LDS (fp16 RNE), Mt B-frags.
//   2 barriers/tile; Mh+Mt double-buffered; DMA issued so each barrier's
//   vmcnt(0) drain covers ~32KB landed during the preceding compute phase.
// combine: merge 2 halves' (m,l,O), gate, blend with N, store.

constexpr int EMBED = 256;
constexpr int BQ = 64;
constexpr int BJ = 64;
constexpr int NT = 512;

// LDS offsets (bytes)
constexpr int MH0 = 0;                  // 64 j x 512 B (fp16 row plane)
constexpr int MH1 = 32768;
constexpr int MT0 = 65536;              // 256 d x 128 B (fp16 transposed plane)
constexpr int MT1 = 98304;
constexpr int SS_O = 131072;            // 64 x 68 f32 scores
constexpr int PH_O = SS_O + 64 * 68 * 4;   // 64 x 144 B (64 fp16 + pad)
constexpr int MS_O = PH_O + 64 * 144;
constexpr int LS_O = MS_O + 256;
constexpr int AS_O = LS_O + 256;
constexpr int LDS_TOTAL = AS_O + 256;   // 158464 <= 163840

typedef _Float16 half8 __attribute__((ext_vector_type(8)));
typedef float f32x4 __attribute__((ext_vector_type(4)));
typedef short short8v __attribute__((ext_vector_type(8)));

static __device__ __forceinline__ f32x4 mfma16(half8 a, half8 b, f32x4 c) {
    return __builtin_amdgcn_mfma_f32_16x16x32_f16(a, b, c, 0, 0, 0);
}
static __device__ __forceinline__ void gld_lds16(const void* g, void* l) {
    __builtin_amdgcn_global_load_lds((const __attribute__((address_space(1))) unsigned int*)g,
                                     (__attribute__((address_space(3))) unsigned int*)l, 16, 0, 0);
}
static __device__ __forceinline__ short f2h(float x) {
    return (short)__builtin_bit_cast(unsigned short, (_Float16)x);
}

// ---------- prep A: fp16 row plane, XOR(j&7) 16B-chunk swizzle ----------
__global__ void prep_h(const float* __restrict__ M, short* __restrict__ MhG) {
    int g = blockIdx.x * 256 + threadIdx.x;   // n*16 threads
    int j = g >> 4, seg = g & 15;             // 32B (2 chunks) per thread
    const float* src = M + (size_t)j * EMBED + seg * 16;
    short8v cA, cB;
    #pragma unroll
    for (int i = 0; i < 4; ++i) {
        float4 v = *(const float4*)(src + 4 * i);
        float xs[4] = {v.x, v.y, v.z, v.w};
        #pragma unroll
        for (int e = 0; e < 4; ++e) {
            int idx = 4 * i + e;
            short h = f2h(xs[e]);
            if (idx < 8) cA[idx] = h; else cB[idx - 8] = h;
        }
    }
    int key = j & 7;
    short* row = MhG + (size_t)j * 256;
    *(short8v*)(row + (((2 * seg) ^ key) * 8)) = cA;
    *(short8v*)(row + (((2 * seg + 1) ^ key) * 8)) = cB;
}

// ---------- prep B: tile-major transposed fp16 plane (LDS image) ----------
__global__ void prep_t(const float* __restrict__ M, short* __restrict__ MtG) {
    __shared__ float L[64 * 260];
    int tau = blockIdx.x;          // global 64-row tile
    int t = threadIdx.x;
    {
        int lj = t >> 2, cc = (t & 3) * 64;
        const float* src = M + (size_t)(tau * 64 + lj) * EMBED + cc;
        #pragma unroll
        for (int i = 0; i < 16; ++i)
            *(float4*)&L[lj * 260 + cc + 4 * i] = *(const float4*)(src + 4 * i);
    }
    __syncthreads();
    {
        int d = t;                                     // 0..255
        short* dst = MtG + (size_t)tau * (64 * EMBED) + d * 64;
        int key = d & 7;
        #pragma unroll
        for (int p = 0; p < 8; ++p) {                  // stored chunk position
            int lc = p ^ key;                          // logical j-chunk
            short8v c;
            #pragma unroll
            for (int e = 0; e < 8; ++e)
                c[e] = f2h(L[(lc * 8 + e) * 260 + d]);
            *(short8v*)(dst + p * 8) = c;
        }
    }
}

// ---------- main split-j flash kernel ----------
__launch_bounds__(NT, 1)
__global__ void attn_split(const short* __restrict__ MhG, const short* __restrict__ MtG,
                           const float* __restrict__ Ng, const int* __restrict__ iseval_p,
                           float* __restrict__ O0out, float* __restrict__ O1out,
                           float* __restrict__ MLm, float* __restrict__ MLl, int n)
{
    __shared__ __align__(16) char smem[LDS_TOTAL];
    float* SS = (float*)(smem + SS_O);
    short* PH = (short*)(smem + PH_O);
    float* MS = (float*)(smem + MS_O);
    float* LS = (float*)(smem + LS_O);
    float* AS = (float*)(smem + AS_O);

    const int t = threadIdx.x, lane = t & 63, wave = t >> 6;
    const int quad = lane >> 4, mn = lane & 15;
    const int qb = blockIdx.x >> 1, half = blockIdx.x & 1;
    const int q0 = qb * BQ;
    const int jbase = half * (n >> 1);
    const int ntiles = (n >> 1) / BJ;
    const int iseval = *iseval_p;
    const int jt = wave & 3, qp = wave >> 2;   // QK roles
    const int dg = wave & 3, qh2 = wave >> 2;  // PV roles
    const int sq = t >> 3, sh = t & 7;         // softmax roles

    if (t < BQ) { MS[t] = -1e30f; LS[t] = 0.f; }

    // ---- Q fragments fp16 (A-layout): Qf[qi][ks], q-tiles {2qp, 2qp+1} ----
    half8 Qf[2][8];
    #pragma unroll
    for (int qi = 0; qi < 2; ++qi) {
        const float* np = Ng + (size_t)(q0 + (2 * qp + qi) * 16 + mn) * EMBED;
        #pragma unroll
        for (int ks = 0; ks < 8; ++ks) {
            const float* p = np + ks * 32 + quad * 8;
            float4 a = *(const float4*)p, b = *(const float4*)(p + 4);
            half8 h;
            h[0]=(_Float16)a.x; h[1]=(_Float16)a.y; h[2]=(_Float16)a.z; h[3]=(_Float16)a.w;
            h[4]=(_Float16)b.x; h[5]=(_Float16)b.y; h[6]=(_Float16)b.z; h[7]=(_Float16)b.w;
            Qf[qi][ks] = h;
        }
    }

    // ---- stage tile 0 into buffers 0 ----
    {
        const char* mh = (const char*)(MhG + (size_t)jbase * EMBED);
        const char* mt = (const char*)(MtG + (size_t)jbase * EMBED);  // tile-major
        #pragma unroll
        for (int i = 0; i < 4; ++i) {
            int cb = wave * 4 + i;
            gld_lds16(mh + cb * 1024 + lane * 16, smem + MH0 + cb * 1024);
            gld_lds16(mt + cb * 1024 + lane * 16, smem + MT0 + cb * 1024);
        }
    }

    f32x4 O[2][4];
    #pragma unroll
    for (int qi = 0; qi < 2; ++qi)
        #pragma unroll
        for (int dt = 0; dt < 4; ++dt) O[qi][dt] = (f32x4){0.f, 0.f, 0.f, 0.f};

    __syncthreads();

    const int brow = jt * 16 + mn;        // QK B-row (local j)
    const int bkey = brow & 7;

    for (int tile = 0; tile < ntiles; ++tile) {
        const int cur = tile & 1;
        const char* mhc = smem + (cur ? MH1 : MH0);
        char*       mhn = smem + (cur ? MH0 : MH1);
        const char* mtc = smem + (cur ? MT1 : MT0);
        char*       mtn = smem + (cur ? MT0 : MT1);
        const int j0g = jbase + tile * BJ;
        const bool hn = (tile + 1) < ntiles;

        // --- issue next Mh DMA (lands during QK; drained at barrier1) ---
        if (hn) {
            const char* mh = (const char*)(MhG + (size_t)(j0g + BJ) * EMBED);
            #pragma unroll
            for (int i = 0; i < 4; ++i) {
                int cb = wave * 4 + i;
                gld_lds16(mh + cb * 1024 + lane * 16, mhn + cb * 1024);
            }
        }

        // --- QK^T (fp16): 2 q-tiles x 1 j-tile, full K ---
        {
            f32x4 a0 = (f32x4){0.f,0.f,0.f,0.f}, a1 = (f32x4){0.f,0.f,0.f,0.f};
            #pragma unroll
            for (int ks = 0; ks < 8; ++ks) {
                half8 bf = *(const half8*)(mhc + brow * 512 + (((4 * ks + quad) ^ bkey) << 4));
                a0 = mfma16(Qf[0][ks], bf, a0);
                a1 = mfma16(Qf[1][ks], bf, a1);
            }
            #pragma unroll
            for (int r = 0; r < 4; ++r) {
                SS[((2 * qp) * 16 + quad * 4 + r) * 68 + jt * 16 + mn]     = a0[r];
                SS[((2 * qp + 1) * 16 + quad * 4 + r) * 68 + jt * 16 + mn] = a1[r];
            }
        }
        __syncthreads();   // barrier1: SS ready, Mh DMA drained

        // --- issue next Mt DMA (PV(tile-1) done per barrier1; lands in softmax) ---
        if (hn) {
            const char* mt = (const char*)(MtG + (size_t)(j0g + BJ) * EMBED);
            #pragma unroll
            for (int i = 0; i < 4; ++i) {
                int cb = wave * 4 + i;
                gld_lds16(mt + cb * 1024 + lane * 16, mtn + cb * 1024);
            }
        }

        // --- online softmax: thread (sq, sh) owns j = 8sh..8sh+7 ---
        {
            float4 sa = *(const float4*)(SS + sq * 68 + 8 * sh);
            float4 sb = *(const float4*)(SS + sq * 68 + 8 * sh + 4);
            float s[8] = {sa.x, sa.y, sa.z, sa.w, sb.x, sb.y, sb.z, sb.w};
            const int qg = q0 + sq;
            if (iseval) {
                if (qg == 0) {
                    #pragma unroll
                    for (int i = 0; i < 8; ++i) s[i] = 0.f;
                }
            } else {
                int dj = qg - j0g - 8 * sh;
                #pragma unroll
                for (int i = 0; i < 8; ++i) if (dj == i) s[i] = 0.f;
            }
            float mx = s[0];
            #pragma unroll
            for (int i = 1; i < 8; ++i) mx = fmaxf(mx, s[i]);
            mx = fmaxf(mx, __shfl_xor(mx, 1));
            mx = fmaxf(mx, __shfl_xor(mx, 2));
            mx = fmaxf(mx, __shfl_xor(mx, 4));
            float m_old = MS[sq];
            float m_new = fmaxf(m_old, mx);
            float alpha = __expf(m_old - m_new);
            float p[8], ps = 0.f;
            #pragma unroll
            for (int i = 0; i < 8; ++i) { p[i] = __expf(s[i] - m_new); ps += p[i]; }
            ps += __shfl_xor(ps, 1);
            ps += __shfl_xor(ps, 2);
            ps += __shfl_xor(ps, 4);
            if (sh == 0) {
                MS[sq] = m_new;
                AS[sq] = alpha;
                LS[sq] = LS[sq] * alpha + ps;
            }
            half8 ph;
            #pragma unroll
            for (int i = 0; i < 8; ++i) ph[i] = (_Float16)p[i];
            *(half8*)((char*)PH + sq * 144 + sh * 16) = ph;
        }
        __syncthreads();   // barrier2: PH/AS ready, Mt DMA drained

        // --- PV (fp16): 2 q-tiles x 4 d-tiles, K=64 (2 steps) ---
        {
            float aq[2][4];
            #pragma unroll
            for (int qi = 0; qi < 2; ++qi)
                #pragma unroll
                for (int r = 0; r < 4; ++r)
                    aq[qi][r] = AS[(2 * qh2 + qi) * 16 + quad * 4 + r];
            half8 pa[2][2];
            #pragma unroll
            for (int qi = 0; qi < 2; ++qi)
                #pragma unroll
                for (int k2 = 0; k2 < 2; ++k2)
                    pa[qi][k2] = *(const half8*)((char*)PH + ((2 * qh2 + qi) * 16 + mn) * 144 + k2 * 64 + quad * 16);
            #pragma unroll
            for (int dt = 0; dt < 4; ++dt) {
                int d = (4 * dg + dt) * 16 + mn;
                const char* base = mtc + d * 128;
                int key = d & 7;
                half8 b0 = *(const half8*)(base + (((quad) ^ key) << 4));
                half8 b1 = *(const half8*)(base + (((4 + quad) ^ key) << 4));
                #pragma unroll
                for (int qi = 0; qi < 2; ++qi) {
                    f32x4 o = O[qi][dt];
                    o[0] *= aq[qi][0]; o[1] *= aq[qi][1]; o[2] *= aq[qi][2]; o[3] *= aq[qi][3];
                    o = mfma16(pa[qi][0], b0, o);
                    o = mfma16(pa[qi][1], b1, o);
                    O[qi][dt] = o;
                }
            }
        }
        // no 3rd barrier: QK(t+1) touches only Mh/SS; softmax(t+1) (which
        // overwrites PH/AS) is fenced by barrier1(t+1); next Mh DMA targets
        // the buffer all waves finished reading before barrier1(t).
    }

    // ---- epilogue: write partial O (unnormalized) + (m,l) ----
    {
        float* dst = half ? O1out : O0out;
        #pragma unroll
        for (int qi = 0; qi < 2; ++qi) {
            int qtb = q0 + (2 * qh2 + qi) * 16;
            #pragma unroll
            for (int dt = 0; dt < 4; ++dt) {
                int col = (4 * dg + dt) * 16 + mn;
                #pragma unroll
                for (int r = 0; r < 4; ++r)
                    dst[(size_t)(qtb + quad * 4 + r) * EMBED + col] = O[qi][dt][r];
            }
        }
    }
    __syncthreads();
    if (t < BQ) {
        MLm[half * n + q0 + t] = MS[t];
        MLl[half * n + q0 + t] = LS[t];
    }
}

// ---------- combine halves + gate + blend ----------
__global__ void combine(const float* __restrict__ O0, const float* __restrict__ O1,
                        const float* __restrict__ MLm, const float* __restrict__ MLl,
                        const float* __restrict__ Ng, const float* __restrict__ Wg,
                        const float* __restrict__ bg, const float* __restrict__ gb,
                        float* __restrict__ out, int n)
{
    int t = threadIdx.x;
    int row = blockIdx.x * 8 + (t >> 5);
    int c = t & 31;
    float m0 = MLm[row], m1 = MLm[n + row];
    float l0 = MLl[row], l1 = MLl[n + row];
    float m = fmaxf(m0, m1);
    float w0 = __expf(m0 - m), w1 = __expf(m1 - m);
    float linv = 1.f / (w0 * l0 + w1 * l1);
    const float4* o0 = (const float4*)(O0 + (size_t)row * EMBED + c * 8);
    const float4* o1 = (const float4*)(O1 + (size_t)row * EMBED + c * 8);
    const float4* w4 = (const float4*)(Wg + c * 8);
    float4 oa[2];
    float dot = 0.f;
    #pragma unroll
    for (int i = 0; i < 2; ++i) {
        float4 a = o0[i], b = o1[i], w = w4[i];
        float4 o;
        o.x = (w0 * a.x + w1 * b.x) * linv;
        o.y = (w0 * a.y + w1 * b.y) * linv;
        o.z = (w0 * a.z + w1 * b.z) * linv;
        o.w = (w0 * a.w + w1 * b.w) * linv;
        dot += o.x * w.x + o.y * w.y + o.z * w.z + o.w * w.w;
        oa[i] = o;
    }
    dot += __shfl_xor(dot, 1);
    dot += __shfl_xor(dot, 2);
    dot += __shfl_xor(dot, 4);
    dot += __shfl_xor(dot, 8);
    dot += __shfl_xor(dot, 16);
    float g = 1.f / (1.f + __expf(-(dot + bg[0] + gb[0])));
    const float4* n4 = (const float4*)(Ng + (size_t)row * EMBED + c * 8);
    float4* ot = (float4*)(out + (size_t)row * EMBED + c * 8);
    #pragma unroll
    for (int i = 0; i < 2; ++i) {
        float4 nn = n4[i];
        float4 res;
        res.x = oa[i].x * g + nn.x * (1.f - g);
        res.y = oa[i].y * g + nn.y * (1.f - g);
        res.z = oa[i].z * g + nn.z * (1.f - g);
        res.w = oa[i].w * g + nn.w * (1.f - g);
        ot[i] = res;
    }
}

extern "C" void kernel_launch(void* const* d_in, const int* in_sizes, int n_in,
                              void* d_out, int out_size, void* d_ws, size_t ws_size,
                              hipStream_t stream) {
    const float* M      = (const float*)d_in[0];
    const float* N      = (const float*)d_in[1];
    const float* Wgp    = (const float*)d_in[2];
    const float* bgp    = (const float*)d_in[3];
    const float* gbp    = (const float*)d_in[4];
    const int*   iseval = (const int*)d_in[5];
    float* out = (float*)d_out;

    int n = in_sizes[0] / EMBED;   // 8192
    short* MhG = (short*)d_ws;                         // n*256 fp16 = 4 MB
    short* MtG = MhG + (size_t)n * EMBED;              // n*256 fp16 = 4 MB (tile-major)
    float* O1  = (float*)(MtG + (size_t)n * EMBED);    // n*256 f32  = 8 MB
    float* MLm = O1 + (size_t)n * EMBED;               // 2n f32
    float* MLl = MLm + 2 * n;                          // 2n f32
    // ws required: ~16.9 MB

    hipLaunchKernelGGL(prep_h, dim3(n * 16 / 256), dim3(256), 0, stream, M, MhG);
    hipLaunchKernelGGL(prep_t, dim3(n / 64), dim3(256), 0, stream, M, MtG);
    hipLaunchKernelGGL(attn_split, dim3((n / BQ) * 2), dim3(NT), 0, stream,
                       MhG, MtG, N, iseval, out, O1, MLm, MLl, n);
    hipLaunchKernelGGL(combine, dim3(n / 8), dim3(256), 0, stream,
                       out, O1, MLm, MLl, N, Wgp, bgp, gbp, out, n);
}

// Round 5
// 217.727 us; speedup vs baseline: 13.8390x; 1.0844x over previous
//
#include <hip/hip_runtime.h>

// AttentionMatcher R5: 2 blocks/CU overlap + 4-way split-j + fused prep.
// out = gate * softmax(N M^T, diag<-0) M + (1-gate) * N,  n=8192, d=256, fp32.
//
// ws: MhG [n][256] fp16 RNE, 16B-chunk XOR(j&7)-swizzled rows  (QK B-plane)
//     MtG tile-major: per 32-j tile, 128 d-pair blocks of 128B; chunk at
//         position p holds c = p ^ (P&7), c = (d&1)*4 + jchunk  -> exact LDS
//         image, gld_lds16-staged, 2-way (free) banks for PV b128 reads.
//     Ofp: 3 fp16 partial O planes (split s=1..3); s=0 partial f32 in d_out.
//     MLm/MLl [4][n] f32 running max / sum per split.
//
// attn_split4: grid 512 = (128 q-blocks x 4 j-quarters), 256 thr (4 waves),
//   BQ=64, BJ=32, LDS 78.8 KB -> 2 blocks/CU. 2 barriers/tile, dbuf DMA.
// combine4: merge 4 partials, gate, blend with N.

constexpr int EMBED = 256;
constexpr int BQ = 64;
constexpr int BJ = 32;
constexpr int NT = 256;

// LDS offsets (bytes)
constexpr int MH0  = 0;            // 32 j x 512 B
constexpr int MH1  = 16384;
constexpr int MT0  = 32768;        // 128 d-pairs x 128 B
constexpr int MT1  = 49152;
constexpr int SS_O = 65536;        // 64 x 36 f32
constexpr int PH_O = 74752;        // 64 x 80 B (32 fp16 + pad)
constexpr int MS_O = 79872;        // 64 f32
constexpr int LS_O = 80128;
constexpr int AS_O = 80384;
constexpr int LDS_TOTAL = 80640;   // x2 blocks = 161280 <= 163840

typedef _Float16 half8 __attribute__((ext_vector_type(8)));
typedef float f32x4 __attribute__((ext_vector_type(4)));
typedef short short8v __attribute__((ext_vector_type(8)));

static __device__ __forceinline__ f32x4 mfma16(half8 a, half8 b, f32x4 c) {
    return __builtin_amdgcn_mfma_f32_16x16x32_f16(a, b, c, 0, 0, 0);
}
static __device__ __forceinline__ void gld_lds16(const void* g, void* l) {
    __builtin_amdgcn_global_load_lds((const __attribute__((address_space(1))) unsigned int*)g,
                                     (__attribute__((address_space(3))) unsigned int*)l, 16, 0, 0);
}
static __device__ __forceinline__ short f2h(float x) {
    return (short)__builtin_bit_cast(unsigned short, (_Float16)x);
}

// ---------- fused prep: one M pass -> Mh row plane + Mt tile plane ----------
__global__ void prep(const float* __restrict__ M,
                     short* __restrict__ MhG, short* __restrict__ MtG) {
    __shared__ float L[32 * 260];
    const int blk = blockIdx.x;       // one 32-j tile
    const int t = threadIdx.x;
    {
        const float* src = M + (size_t)(blk * 32 + (t >> 3)) * EMBED + (t & 7) * 32;
        float* lr = L + (t >> 3) * 260 + (t & 7) * 32;
        #pragma unroll
        for (int i = 0; i < 8; ++i)
            *(float4*)(lr + 4 * i) = *(const float4*)(src + 4 * i);
    }
    __syncthreads();
    {   // Mh: row j, 32 chunks of 8 fp16, position = c ^ (j&7)
        const int j = t >> 3, key = j & 7;
        short* dst = MhG + (size_t)(blk * 32 + j) * 256;
        #pragma unroll
        for (int cc = 0; cc < 4; ++cc) {
            int c = (t & 7) * 4 + cc;
            short8v v;
            #pragma unroll
            for (int e = 0; e < 8; ++e) v[e] = f2h(L[j * 260 + c * 8 + e]);
            *(short8v*)(dst + (c ^ key) * 8) = v;
        }
    }
    {   // Mt: d-pair P block of 128B, chunk pos p holds c=p^(P&7),
        // c=(d&1)*4+jc, content M[jc*8+e][2P+(c>>2)]
        const int P = t >> 1, hv = t & 1;
        short* dst = MtG + (size_t)blk * 8192 + P * 64;
        #pragma unroll
        for (int pp = 0; pp < 4; ++pp) {
            int p = hv * 4 + pp;
            int c = p ^ (P & 7);
            int d = 2 * P + (c >> 2), jc = c & 3;
            short8v v;
            #pragma unroll
            for (int e = 0; e < 8; ++e) v[e] = f2h(L[(jc * 8 + e) * 260 + d]);
            *(short8v*)(dst + p * 8) = v;
        }
    }
}

// ---------- main 4-way split-j flash kernel ----------
__launch_bounds__(NT, 2)
__global__ void attn_split4(const short* __restrict__ MhG, const short* __restrict__ MtG,
                            const float* __restrict__ Ng, const int* __restrict__ iseval_p,
                            float* __restrict__ O0out, short* __restrict__ Ofp,
                            float* __restrict__ MLm, float* __restrict__ MLl, int n)
{
    __shared__ __align__(16) char smem[LDS_TOTAL];
    float* SS = (float*)(smem + SS_O);
    float* MS = (float*)(smem + MS_O);
    float* LS = (float*)(smem + LS_O);
    float* AS = (float*)(smem + AS_O);

    const int t = threadIdx.x, lane = t & 63, wave = t >> 6;
    const int quad = lane >> 4, mn = lane & 15;
    const int qb = blockIdx.x & 127, s = blockIdx.x >> 7;
    const int q0 = qb * BQ;
    const int jbase = s * (n >> 2);
    const int ntiles = (n >> 2) / BJ;          // 64
    const int iseval = *iseval_p;
    const int qp = wave >> 1;                  // q-pair: tiles 2qp, 2qp+1
    const int jt = wave & 1;                   // QK j-tile
    const int dh = wave & 1;                   // PV d-half
    const int sq = t >> 2, sh = t & 3;         // softmax: 4 thr/row, 8 j each

    if (t < BQ) { MS[t] = -1e30f; LS[t] = 0.f; }

    // ---- Q fragments fp16 (A-layout) ----
    half8 Qf[2][8];
    #pragma unroll
    for (int qi = 0; qi < 2; ++qi) {
        const float* np = Ng + (size_t)(q0 + (2 * qp + qi) * 16 + mn) * EMBED;
        #pragma unroll
        for (int ks = 0; ks < 8; ++ks) {
            const float* p = np + ks * 32 + quad * 8;
            float4 a = *(const float4*)p, b = *(const float4*)(p + 4);
            half8 h;
            h[0]=(_Float16)a.x; h[1]=(_Float16)a.y; h[2]=(_Float16)a.z; h[3]=(_Float16)a.w;
            h[4]=(_Float16)b.x; h[5]=(_Float16)b.y; h[6]=(_Float16)b.z; h[7]=(_Float16)b.w;
            Qf[qi][ks] = h;
        }
    }

    // ---- stage tile 0 (both planes are 512 B per j-row => same offset calc) ----
    {
        const char* mh = (const char*)MhG + (size_t)jbase * 512;
        const char* mt = (const char*)MtG + (size_t)jbase * 512;
        #pragma unroll
        for (int i = 0; i < 4; ++i) {
            int cb = wave * 4 + i;
            gld_lds16(mh + cb * 1024 + lane * 16, smem + MH0 + cb * 1024);
            gld_lds16(mt + cb * 1024 + lane * 16, smem + MT0 + cb * 1024);
        }
    }

    f32x4 O[2][8];
    #pragma unroll
    for (int qi = 0; qi < 2; ++qi)
        #pragma unroll
        for (int dt = 0; dt < 8; ++dt) O[qi][dt] = (f32x4){0.f, 0.f, 0.f, 0.f};

    __syncthreads();

    const int brow = jt * 16 + mn;
    const int bkey = brow & 7;

    for (int tile = 0; tile < ntiles; ++tile) {
        const int cur = tile & 1;
        const char* mhc = smem + (cur ? MH1 : MH0);
        char*       mhn = smem + (cur ? MH0 : MH1);
        const char* mtc = smem + (cur ? MT1 : MT0);
        char*       mtn = smem + (cur ? MT0 : MT1);
        const int j0g = jbase + tile * BJ;
        const bool hn = (tile + 1) < ntiles;

        // --- issue next Mh DMA (target buf fenced by barrier1(tile-1)) ---
        if (hn) {
            const char* mh = (const char*)MhG + (size_t)(j0g + BJ) * 512;
            #pragma unroll
            for (int i = 0; i < 4; ++i) {
                int cb = wave * 4 + i;
                gld_lds16(mh + cb * 1024 + lane * 16, mhn + cb * 1024);
            }
        }

        // --- QK^T (fp16): 2 q-tiles x 1 j-tile x K=256 ---
        {
            f32x4 a0 = (f32x4){0.f,0.f,0.f,0.f}, a1 = (f32x4){0.f,0.f,0.f,0.f};
            #pragma unroll
            for (int ks = 0; ks < 8; ++ks) {
                half8 bf = *(const half8*)(mhc + brow * 512 + (((4 * ks + quad) ^ bkey) << 4));
                a0 = mfma16(Qf[0][ks], bf, a0);
                a1 = mfma16(Qf[1][ks], bf, a1);
            }
            #pragma unroll
            for (int r = 0; r < 4; ++r) {
                SS[((2 * qp) * 16 + quad * 4 + r) * 36 + jt * 16 + mn]     = a0[r];
                SS[((2 * qp + 1) * 16 + quad * 4 + r) * 36 + jt * 16 + mn] = a1[r];
            }
        }
        __syncthreads();   // barrier1: SS ready; Mh DMA drained

        // --- issue next Mt DMA (target buf's readers fenced by barrier1) ---
        if (hn) {
            const char* mt = (const char*)MtG + (size_t)(j0g + BJ) * 512;
            #pragma unroll
            for (int i = 0; i < 4; ++i) {
                int cb = wave * 4 + i;
                gld_lds16(mt + cb * 1024 + lane * 16, mtn + cb * 1024);
            }
        }

        // --- online softmax: thread (sq, sh) owns j = 8sh..8sh+7 ---
        {
            float4 sa = *(const float4*)(SS + sq * 36 + 8 * sh);
            float4 sb = *(const float4*)(SS + sq * 36 + 8 * sh + 4);
            float sv[8] = {sa.x, sa.y, sa.z, sa.w, sb.x, sb.y, sb.z, sb.w};
            const int qg = q0 + sq;
            if (iseval) {
                if (qg == 0) {
                    #pragma unroll
                    for (int i = 0; i < 8; ++i) sv[i] = 0.f;
                }
            } else {
                int dj = qg - j0g - 8 * sh;
                #pragma unroll
                for (int i = 0; i < 8; ++i) if (dj == i) sv[i] = 0.f;
            }
            float mx = sv[0];
            #pragma unroll
            for (int i = 1; i < 8; ++i) mx = fmaxf(mx, sv[i]);
            mx = fmaxf(mx, __shfl_xor(mx, 1));
            mx = fmaxf(mx, __shfl_xor(mx, 2));
            float m_old = MS[sq];
            float m_new = fmaxf(m_old, mx);
            float alpha = __expf(m_old - m_new);
            float p[8], ps = 0.f;
            #pragma unroll
            for (int i = 0; i < 8; ++i) { p[i] = __expf(sv[i] - m_new); ps += p[i]; }
            ps += __shfl_xor(ps, 1);
            ps += __shfl_xor(ps, 2);
            if (sh == 0) {
                MS[sq] = m_new;
                AS[sq] = alpha;
                LS[sq] = LS[sq] * alpha + ps;
            }
            half8 ph;
            #pragma unroll
            for (int i = 0; i < 8; ++i) ph[i] = (_Float16)p[i];
            *(half8*)(smem + PH_O + sq * 80 + sh * 16) = ph;
        }
        __syncthreads();   // barrier2: PH/AS ready; Mt DMA drained

        // --- PV (fp16): 2 q-tiles x 8 d-tiles x K=32 ---
        {
            float aq[2][4];
            #pragma unroll
            for (int qi = 0; qi < 2; ++qi)
                #pragma unroll
                for (int r = 0; r < 4; ++r)
                    aq[qi][r] = AS[(2 * qp + qi) * 16 + quad * 4 + r];
            half8 pa[2];
            #pragma unroll
            for (int qi = 0; qi < 2; ++qi)
                pa[qi] = *(const half8*)(smem + PH_O + ((2 * qp + qi) * 16 + mn) * 80 + quad * 16);
            #pragma unroll
            for (int dt = 0; dt < 8; ++dt) {
                int d = dh * 128 + dt * 16 + mn;
                int P2 = d >> 1;
                int p = ((d & 1) * 4 + quad) ^ (P2 & 7);
                half8 bf = *(const half8*)(mtc + P2 * 128 + p * 16);
                #pragma unroll
                for (int qi = 0; qi < 2; ++qi) {
                    f32x4 o = O[qi][dt];
                    o[0] *= aq[qi][0]; o[1] *= aq[qi][1]; o[2] *= aq[qi][2]; o[3] *= aq[qi][3];
                    O[qi][dt] = mfma16(pa[qi], bf, o);
                }
            }
        }
        // no 3rd barrier: next QK touches only Mh/SS (fenced by barrier1(t+1));
        // next Mh DMA targets the buffer fenced by barrier1 of this tile.
    }

    // ---- epilogue: partial O + (m,l) ----
    if (s == 0) {
        #pragma unroll
        for (int qi = 0; qi < 2; ++qi) {
            int qtb = q0 + (2 * qp + qi) * 16;
            #pragma unroll
            for (int dt = 0; dt < 8; ++dt) {
                int col = dh * 128 + dt * 16 + mn;
                #pragma unroll
                for (int r = 0; r < 4; ++r)
                    O0out[(size_t)(qtb + quad * 4 + r) * EMBED + col] = O[qi][dt][r];
            }
        }
    } else {
        short* dst = Ofp + (size_t)(s - 1) * n * EMBED;
        #pragma unroll
        for (int qi = 0; qi < 2; ++qi) {
            int qtb = q0 + (2 * qp + qi) * 16;
            #pragma unroll
            for (int dt = 0; dt < 8; ++dt) {
                int col = dh * 128 + dt * 16 + mn;
                #pragma unroll
                for (int r = 0; r < 4; ++r)
                    dst[(size_t)(qtb + quad * 4 + r) * EMBED + col] = f2h(O[qi][dt][r]);
            }
        }
    }
    if (t < BQ) {
        MLm[s * n + q0 + t] = MS[t];
        MLl[s * n + q0 + t] = LS[t];
    }
}

// ---------- combine 4 partials + gate + blend ----------
__global__ void combine4(const float* __restrict__ O0, const short* __restrict__ Ofp,
                         const float* __restrict__ MLm, const float* __restrict__ MLl,
                         const float* __restrict__ Ng, const float* __restrict__ Wg,
                         const float* __restrict__ bg, const float* __restrict__ gb,
                         float* __restrict__ out, int n)
{
    const int t = threadIdx.x;
    const int row = blockIdx.x * 16 + (t >> 4);
    const int c = t & 15;                      // 16 d-elements per thread
    float ms[4], ls[4];
    #pragma unroll
    for (int s = 0; s < 4; ++s) { ms[s] = MLm[s * n + row]; ls[s] = MLl[s * n + row]; }
    float m = fmaxf(fmaxf(ms[0], ms[1]), fmaxf(ms[2], ms[3]));
    float w[4], lsum = 0.f;
    #pragma unroll
    for (int s = 0; s < 4; ++s) { w[s] = __expf(ms[s] - m); lsum += w[s] * ls[s]; }
    float linv = 1.f / lsum;

    float acc[16];
    {
        const float4* o0 = (const float4*)(O0 + (size_t)row * EMBED + c * 16);
        #pragma unroll
        for (int i = 0; i < 4; ++i) {
            float4 v = o0[i];
            acc[4*i+0] = w[0] * v.x; acc[4*i+1] = w[0] * v.y;
            acc[4*i+2] = w[0] * v.z; acc[4*i+3] = w[0] * v.w;
        }
    }
    #pragma unroll
    for (int s = 1; s < 4; ++s) {
        const short* op = Ofp + (size_t)(s - 1) * n * EMBED + (size_t)row * EMBED + c * 16;
        half8 a = *(const half8*)op, b = *(const half8*)(op + 8);
        #pragma unroll
        for (int i = 0; i < 8; ++i) {
            acc[i]     += w[s] * (float)a[i];
            acc[8 + i] += w[s] * (float)b[i];
        }
    }
    float dot = 0.f;
    #pragma unroll
    for (int i = 0; i < 16; ++i) { acc[i] *= linv; dot += acc[i] * Wg[c * 16 + i]; }
    dot += __shfl_xor(dot, 1);
    dot += __shfl_xor(dot, 2);
    dot += __shfl_xor(dot, 4);
    dot += __shfl_xor(dot, 8);
    float g = 1.f / (1.f + __expf(-(dot + bg[0] + gb[0])));
    const float4* n4 = (const float4*)(Ng + (size_t)row * EMBED + c * 16);
    float4* o4 = (float4*)(out + (size_t)row * EMBED + c * 16);
    #pragma unroll
    for (int i = 0; i < 4; ++i) {
        float4 nn = n4[i];
        float4 res;
        res.x = acc[4*i+0] * g + nn.x * (1.f - g);
        res.y = acc[4*i+1] * g + nn.y * (1.f - g);
        res.z = acc[4*i+2] * g + nn.z * (1.f - g);
        res.w = acc[4*i+3] * g + nn.w * (1.f - g);
        o4[i] = res;
    }
}

extern "C" void kernel_launch(void* const* d_in, const int* in_sizes, int n_in,
                              void* d_out, int out_size, void* d_ws, size_t ws_size,
                              hipStream_t stream) {
    const float* M      = (const float*)d_in[0];
    const float* N      = (const float*)d_in[1];
    const float* Wgp    = (const float*)d_in[2];
    const float* bgp    = (const float*)d_in[3];
    const float* gbp    = (const float*)d_in[4];
    const int*   iseval = (const int*)d_in[5];
    float* out = (float*)d_out;

    int n = in_sizes[0] / EMBED;   // 8192
    short* MhG = (short*)d_ws;                          // n*256 fp16 = 4 MB
    short* MtG = MhG + (size_t)n * EMBED;               // n*256 fp16 = 4 MB
    short* Ofp = MtG + (size_t)n * EMBED;               // 3 * n*256 fp16 = 12 MB
    float* MLm = (float*)(Ofp + (size_t)3 * n * EMBED); // 4n f32
    float* MLl = MLm + 4 * n;                           // 4n f32
    // ws required ~20.3 MB

    hipLaunchKernelGGL(prep, dim3(n / 32), dim3(256), 0, stream, M, MhG, MtG);
    hipLaunchKernelGGL(attn_split4, dim3((n / BQ) * 4), dim3(NT), 0, stream,
                       MhG, MtG, N, iseval, out, Ofp, MLm, MLl, n);
    hipLaunchKernelGGL(combine4, dim3(n / 16), dim3(256), 0, stream,
                       out, Ofp, MLm, MLl, N, Wgp, bgp, gbp, out, n);
}

// Round 7
// 186.931 us; speedup vs baseline: 16.1189x; 1.1647x over previous
//
#include <hip/hip_runtime.h>

// AttentionMatcher R7: 3 kernels; attn reads MFMA B-operands directly from
// L2 (no LDS staging of M). XCD-swizzled splits pin each j-split's fp16
// planes (2 MB) in one XCD's 4 MiB L2.
// out = gate * softmax(N M^T, diag<-0) M + (1-gate) * N,  n=8192, d=256, fp32.
//
// ws: MhG [n][256] fp16 row-major          (QK B-plane)
//     MtG [n/32 tiles][256 d][32 j] fp16   (PV B-plane, transposed tile-major)
//     Ofp 3 fp16 partial O planes (splits 1..3); split-0 partial f32 in d_out
//     MLm/MLl [4][n] f32 running max / sum per split.
//
// attn: 512 blocks (128 q-blocks x 4 splits, XCD-swizzled), 256 thr,
//   launch_bounds(256,2) -> 2 blocks/CU. BQ=64, BJ=32, 64 tiles.
//   QK: wave=(jt,kh): B-frags global->reg, partial SS planes summed in softmax.
//   PV: wave=d-quarter: Mt frags global->reg, P via LDS (fp16).
//   2 barriers/tile; register prefetch crosses barriers freely.

constexpr int EMBED = 256;
constexpr int BQ = 64;
constexpr int BJ = 32;
constexpr int NT = 256;

constexpr int SS_OFF = 0;            // 2 planes x (64 x 36) f32 = 18432 B
constexpr int PH_OFF = 18432;        // 64 x 80 B (32 fp16 + pad)
constexpr int MS_OFF = 23552;
constexpr int LS_OFF = 23808;
constexpr int AS_OFF = 24064;
constexpr int LDS_SZ = 24320;        // x2 blocks/CU = 48.6 KB

typedef _Float16 half8 __attribute__((ext_vector_type(8)));
typedef float f32x4 __attribute__((ext_vector_type(4)));
typedef short short8v __attribute__((ext_vector_type(8)));

static __device__ __forceinline__ f32x4 mfma16(half8 a, half8 b, f32x4 c) {
    return __builtin_amdgcn_mfma_f32_16x16x32_f16(a, b, c, 0, 0, 0);
}
static __device__ __forceinline__ short f2h(float x) {
    return (short)__builtin_bit_cast(unsigned short, (_Float16)x);
}

// ---------- prep: fp16 row plane + fp16 transposed tile plane ----------
__global__ void prep(const float* __restrict__ M,
                     short* __restrict__ MhG, short* __restrict__ MtG) {
    __shared__ float L[16 * 260];
    const int r0 = blockIdx.x * 16;            // 16 M-rows per block
    const int t = threadIdx.x;
    const int pj = t >> 4, pc = (t & 15) * 16;
    {
        const float* src = M + (size_t)(r0 + pj) * EMBED + pc;
        float4 v[4];
        #pragma unroll
        for (int i = 0; i < 4; ++i) v[i] = ((const float4*)src)[i];
        short* hd = MhG + (size_t)(r0 + pj) * EMBED + pc;
        #pragma unroll
        for (int i = 0; i < 2; ++i) {
            float4 a = v[2 * i], b = v[2 * i + 1];
            short8v h;
            h[0]=f2h(a.x); h[1]=f2h(a.y); h[2]=f2h(a.z); h[3]=f2h(a.w);
            h[4]=f2h(b.x); h[5]=f2h(b.y); h[6]=f2h(b.z); h[7]=f2h(b.w);
            *(short8v*)(hd + 8 * i) = h;
        }
        #pragma unroll
        for (int i = 0; i < 4; ++i)
            *(float4*)(L + pj * 260 + pc + 4 * i) = v[i];
    }
    __syncthreads();
    {
        const int d = t;                        // 0..255
        const int tile = r0 >> 5, jh = (r0 >> 4) & 1;
        short* dst = MtG + (size_t)tile * (BJ * EMBED) + d * BJ + jh * 16;
        #pragma unroll
        for (int g2 = 0; g2 < 2; ++g2) {
            short8v w;
            #pragma unroll
            for (int e = 0; e < 8; ++e) w[e] = f2h(L[(g2 * 8 + e) * 260 + d]);
            *(short8v*)(dst + g2 * 8) = w;
        }
    }
}

// ---------- main split-j flash kernel (direct-from-L2 B-operands) ----------
__launch_bounds__(NT, 2)
__global__ void attn(const short* __restrict__ MhG, const short* __restrict__ MtG,
                     const float* __restrict__ Ng, const int* __restrict__ iseval_p,
                     float* __restrict__ O0out, short* __restrict__ Ofp,
                     float* __restrict__ MLm, float* __restrict__ MLl, int n)
{
    __shared__ __align__(16) char smem[LDS_SZ];
    float* MS = (float*)(smem + MS_OFF);
    float* LS = (float*)(smem + LS_OFF);
    float* AS = (float*)(smem + AS_OFF);

    const int t = threadIdx.x, lane = t & 63, wave = t >> 6;
    const int quad = lane >> 4, mn = lane & 15;
    // XCD swizzle: bid%8 -> XCD; all 64 blocks on an XCD share one split s.
    const int bid = blockIdx.x;
    const int s  = (bid & 7) >> 1;               // split 0..3
    const int qb = ((bid >> 3) << 1) | (bid & 1);// 0..127
    const int q0 = qb * BQ;
    const int jbase = s * (n >> 2);
    const int jb32 = jbase / BJ;
    const int ntiles = (n >> 2) / BJ;            // 64
    const int iseval = *iseval_p;
    const int jt = wave & 1, kh = wave >> 1;     // QK roles
    const int dq = wave;                         // PV d-quarter
    const int sq = t >> 2, sh = t & 3;           // softmax roles

    if (t < BQ) { MS[t] = -1e30f; LS[t] = 0.f; }

    // ---- Q fragments fp16 (A-layout): this wave's K-half only ----
    half8 Qf[4][4];
    #pragma unroll
    for (int qi = 0; qi < 4; ++qi) {
        const float* np = Ng + (size_t)(q0 + qi * 16 + mn) * EMBED;
        #pragma unroll
        for (int kk = 0; kk < 4; ++kk) {
            const float* p = np + (kh * 4 + kk) * 32 + quad * 8;
            float4 a = *(const float4*)p, b = *(const float4*)(p + 4);
            half8 h;
            h[0]=(_Float16)a.x; h[1]=(_Float16)a.y; h[2]=(_Float16)a.z; h[3]=(_Float16)a.w;
            h[4]=(_Float16)b.x; h[5]=(_Float16)b.y; h[6]=(_Float16)b.z; h[7]=(_Float16)b.w;
            Qf[qi][kk] = h;
        }
    }

    f32x4 O[4][4];
    #pragma unroll
    for (int qi = 0; qi < 4; ++qi)
        #pragma unroll
        for (int dt = 0; dt < 4; ++dt) O[qi][dt] = (f32x4){0.f, 0.f, 0.f, 0.f};

    // QK B base: row j = jbase + tile*BJ + jt*16 + mn, cols kh*128 + kk*32 + quad*8
    const short* mhb0 = MhG + (size_t)(jbase + jt * 16 + mn) * EMBED + kh * 128 + quad * 8;
    half8 Bc[4], Bn[4], Mtf[4];
    #pragma unroll
    for (int kk = 0; kk < 4; ++kk) Bc[kk] = *(const half8*)(mhb0 + kk * 32);

    __syncthreads();

    for (int tile = 0; tile < ntiles; ++tile) {
        const int j0g = jbase + tile * BJ;

        // --- QK^T: 4 q-tiles x this wave's (jt, K-half) -> SS plane kh ---
        {
            f32x4 a0 = (f32x4){0,0,0,0}, a1 = (f32x4){0,0,0,0};
            f32x4 a2 = (f32x4){0,0,0,0}, a3 = (f32x4){0,0,0,0};
            #pragma unroll
            for (int kk = 0; kk < 4; ++kk) {
                half8 bf = Bc[kk];
                a0 = mfma16(Qf[0][kk], bf, a0);
                a1 = mfma16(Qf[1][kk], bf, a1);
                a2 = mfma16(Qf[2][kk], bf, a2);
                a3 = mfma16(Qf[3][kk], bf, a3);
            }
            float* ssp = (float*)(smem + SS_OFF) + kh * 2304;
            #pragma unroll
            for (int r = 0; r < 4; ++r) {
                ssp[(0  + quad * 4 + r) * 36 + jt * 16 + mn] = a0[r];
                ssp[(16 + quad * 4 + r) * 36 + jt * 16 + mn] = a1[r];
                ssp[(32 + quad * 4 + r) * 36 + jt * 16 + mn] = a2[r];
                ssp[(48 + quad * 4 + r) * 36 + jt * 16 + mn] = a3[r];
            }
        }
        __syncthreads();   // b1: SS visible

        // --- register prefetch (latency covered by softmax): ---
        if (tile + 1 < ntiles) {
            const short* nb = mhb0 + (size_t)(tile + 1) * (BJ * EMBED);
            #pragma unroll
            for (int kk = 0; kk < 4; ++kk) Bn[kk] = *(const half8*)(nb + kk * 32);
        }
        {
            const short* mtb = MtG + (size_t)(jb32 + tile) * (BJ * EMBED);
            #pragma unroll
            for (int dt = 0; dt < 4; ++dt)
                Mtf[dt] = *(const half8*)(mtb + (dq * 64 + dt * 16 + mn) * BJ + quad * 8);
        }

        // --- online softmax: thread (sq, sh) owns j = 8sh..8sh+7 ---
        {
            const float* p0 = (const float*)(smem + SS_OFF) + sq * 36 + 8 * sh;
            float4 sa = *(const float4*)p0;
            float4 sb = *(const float4*)(p0 + 4);
            float4 sc = *(const float4*)(p0 + 2304);
            float4 sd = *(const float4*)(p0 + 2308);
            float sv[8] = {sa.x + sc.x, sa.y + sc.y, sa.z + sc.z, sa.w + sc.w,
                           sb.x + sd.x, sb.y + sd.y, sb.z + sd.z, sb.w + sd.w};
            const int qg = q0 + sq;
            if (iseval) {
                if (qg == 0) {
                    #pragma unroll
                    for (int i = 0; i < 8; ++i) sv[i] = 0.f;
                }
            } else {
                int dj = qg - j0g - 8 * sh;
                #pragma unroll
                for (int i = 0; i < 8; ++i) if (dj == i) sv[i] = 0.f;
            }
            float mx = sv[0];
            #pragma unroll
            for (int i = 1; i < 8; ++i) mx = fmaxf(mx, sv[i]);
            mx = fmaxf(mx, __shfl_xor(mx, 1));
            mx = fmaxf(mx, __shfl_xor(mx, 2));
            float m_old = MS[sq];
            float m_new = fmaxf(m_old, mx);
            float alpha = __expf(m_old - m_new);
            float p[8], ps = 0.f;
            #pragma unroll
            for (int i = 0; i < 8; ++i) { p[i] = __expf(sv[i] - m_new); ps += p[i]; }
            ps += __shfl_xor(ps, 1);
            ps += __shfl_xor(ps, 2);
            if (sh == 0) {
                MS[sq] = m_new;
                AS[sq] = alpha;
                LS[sq] = LS[sq] * alpha + ps;
            }
            half8 ph;
            #pragma unroll
            for (int i = 0; i < 8; ++i) ph[i] = (_Float16)p[i];
            *(half8*)(smem + PH_OFF + sq * 80 + sh * 16) = ph;
        }
        __syncthreads();   // b2: PH/AS visible

        // --- PV: 4 q-tiles x this wave's 4 d-tiles, K=32 ---
        #pragma unroll
        for (int qi = 0; qi < 4; ++qi) {
            half8 pf = *(const half8*)(smem + PH_OFF + (qi * 16 + mn) * 80 + quad * 16);
            f32x4 al = *(const f32x4*)((const float*)(smem + AS_OFF) + qi * 16 + quad * 4);
            #pragma unroll
            for (int dt = 0; dt < 4; ++dt) {
                f32x4 o = O[qi][dt];
                o[0] *= al[0]; o[1] *= al[1]; o[2] *= al[2]; o[3] *= al[3];
                O[qi][dt] = mfma16(pf, Mtf[dt], o);
            }
        }
        #pragma unroll
        for (int kk = 0; kk < 4; ++kk) Bc[kk] = Bn[kk];
        // SS rewrite (QK t+1) safe: softmax(t) finished reading before b2.
        // PH/AS rewrite (softmax t+1) fenced by b1(t+1), after PV(t).
    }

    // ---- epilogue: partial O + (m,l) per split ----
    if (s == 0) {
        #pragma unroll
        for (int qi = 0; qi < 4; ++qi)
            #pragma unroll
            for (int dt = 0; dt < 4; ++dt) {
                int col = dq * 64 + dt * 16 + mn;
                #pragma unroll
                for (int r = 0; r < 4; ++r)
                    O0out[(size_t)(q0 + qi * 16 + quad * 4 + r) * EMBED + col] = O[qi][dt][r];
            }
    } else {
        short* dst = Ofp + (size_t)(s - 1) * n * EMBED;
        #pragma unroll
        for (int qi = 0; qi < 4; ++qi)
            #pragma unroll
            for (int dt = 0; dt < 4; ++dt) {
                int col = dq * 64 + dt * 16 + mn;
                #pragma unroll
                for (int r = 0; r < 4; ++r)
                    dst[(size_t)(q0 + qi * 16 + quad * 4 + r) * EMBED + col] = f2h(O[qi][dt][r]);
            }
    }
    if (t < BQ) {
        MLm[s * n + q0 + t] = MS[t];
        MLl[s * n + q0 + t] = LS[t];
    }
}

// ---------- combine 4 partials + gate + blend ----------
__global__ void combine4(const float* __restrict__ O0, const short* __restrict__ Ofp,
                         const float* __restrict__ MLm, const float* __restrict__ MLl,
                         const float* __restrict__ Ng, const float* __restrict__ Wg,
                         const float* __restrict__ bg, const float* __restrict__ gb,
                         float* __restrict__ out, int n)
{
    const int t = threadIdx.x;
    const int row = blockIdx.x * 16 + (t >> 4);
    const int c = t & 15;
    float ms[4], ls[4];
    #pragma unroll
    for (int k = 0; k < 4; ++k) { ms[k] = MLm[k * n + row]; ls[k] = MLl[k * n + row]; }
    float m = fmaxf(fmaxf(ms[0], ms[1]), fmaxf(ms[2], ms[3]));
    float w[4], lsum = 0.f;
    #pragma unroll
    for (int k = 0; k < 4; ++k) { w[k] = __expf(ms[k] - m); lsum += w[k] * ls[k]; }
    float linv = 1.f / lsum;

    float acc[16];
    {
        const float4* o0 = (const float4*)(O0 + (size_t)row * EMBED + c * 16);
        #pragma unroll
        for (int i = 0; i < 4; ++i) {
            float4 v = o0[i];
            acc[4*i+0] = w[0] * v.x; acc[4*i+1] = w[0] * v.y;
            acc[4*i+2] = w[0] * v.z; acc[4*i+3] = w[0] * v.w;
        }
    }
    #pragma unroll
    for (int k = 1; k < 4; ++k) {
        const short* op = Ofp + (size_t)(k - 1) * n * EMBED + (size_t)row * EMBED + c * 16;
        half8 a = *(const half8*)op, b = *(const half8*)(op + 8);
        #pragma unroll
        for (int i = 0; i < 8; ++i) {
            acc[i]     += w[k] * (float)a[i];
            acc[8 + i] += w[k] * (float)b[i];
        }
    }
    float dot = 0.f;
    #pragma unroll
    for (int i = 0; i < 16; ++i) { acc[i] *= linv; dot += acc[i] * Wg[c * 16 + i]; }
    dot += __shfl_xor(dot, 1);
    dot += __shfl_xor(dot, 2);
    dot += __shfl_xor(dot, 4);
    dot += __shfl_xor(dot, 8);
    float g = 1.f / (1.f + __expf(-(dot + bg[0] + gb[0])));
    const float4* n4 = (const float4*)(Ng + (size_t)row * EMBED + c * 16);
    float4* o4 = (float4*)(out + (size_t)row * EMBED + c * 16);
    #pragma unroll
    for (int i = 0; i < 4; ++i) {
        float4 nn = n4[i];
        float4 res;
        res.x = acc[4*i+0] * g + nn.x * (1.f - g);
        res.y = acc[4*i+1] * g + nn.y * (1.f - g);
        res.z = acc[4*i+2] * g + nn.z * (1.f - g);
        res.w = acc[4*i+3] * g + nn.w * (1.f - g);
        o4[i] = res;
    }
}

extern "C" void kernel_launch(void* const* d_in, const int* in_sizes, int n_in,
                              void* d_out, int out_size, void* d_ws, size_t ws_size,
                              hipStream_t stream) {
    const float* M      = (const float*)d_in[0];
    const float* N      = (const float*)d_in[1];
    const float* Wgp    = (const float*)d_in[2];
    const float* bgp    = (const float*)d_in[3];
    const float* gbp    = (const float*)d_in[4];
    const int*   iseval = (const int*)d_in[5];
    float* out = (float*)d_out;

    int n = in_sizes[0] / EMBED;   // 8192
    short* MhG = (short*)d_ws;                          // n*256 fp16 = 4 MB
    short* MtG = MhG + (size_t)n * EMBED;               // n*256 fp16 = 4 MB
    short* Ofp = MtG + (size_t)n * EMBED;               // 3*n*256 fp16 = 12 MB
    float* MLm = (float*)(Ofp + (size_t)3 * n * EMBED); // 4n f32
    float* MLl = MLm + 4 * n;                           // 4n f32
    // ws required ~20.3 MB

    hipLaunchKernelGGL(prep, dim3(n / 16), dim3(NT), 0, stream, M, MhG, MtG);
    hipLaunchKernelGGL(attn, dim3((n / BQ) * 4), dim3(NT), 0, stream,
                       MhG, MtG, N, iseval, out, Ofp, MLm, MLl, n);
    hipLaunchKernelGGL(combine4, dim3(n / 16), dim3(NT), 0, stream,
                       out, Ofp, MLm, MLl, N, Wgp, bgp, gbp, out, n);
}